// Round 10
// baseline (106.560 us; speedup 1.0000x reference)
//
#include <hip/hip_runtime.h>
#include <math.h>
#include <limits.h>

#define HH 128
#define WW 128
#define HW (HH*WW)
#define BB 2
#define CC 14
#define NPAIR 26   // B * (C-1)
#define RPB 8                      // rows per block tile
#define NBLK (NPAIR * (HH / RPB))  // 416 blocks
#define NUNIT (2 * BB * HW / 4)    // 16384 uchar4 argmax units (student+teacher)
#define UPB ((NUNIT + NBLK - 1) / NBLK)  // 40 units per block

typedef unsigned long long u64;

// ---------------------------------------------------------------------------
// ws layout (bytes):
//   ps    : [BB][HW] u8  @ 0      (32768)   student argmax labels
//   pt    : [BB][HW] u8  @ 32768  (32768)   teacher argmax labels
//   sums  : [NPAIR] f32  @ 65536  (104)     zeroed by memset node
//   done  : int          @ 65664  (4)       last-block ticket (memset 0)
//   bar   : int          @ 65668  (4)       grid barrier counter (memset 0)
// ---------------------------------------------------------------------------

// distance from row i to nearest set bit in 128-bit mask {lo,hi}; 255 if empty.
__device__ inline int nbd(u64 lo, u64 hi, int i) {
    int up = 255, down = 255;
    u64 slo, shi;
    if (i == 0)      { slo = lo; shi = hi; }
    else if (i < 64) { slo = (lo >> i) | (hi << (64 - i)); shi = hi >> i; }
    else             { slo = hi >> (i - 64); shi = 0ULL; }
    if (slo)      up = __builtin_ctzll(slo);
    else if (shi) up = 64 + __builtin_ctzll(shi);
    int s = 127 - i;
    u64 llo, lhi;
    if (s == 0)      { llo = lo; lhi = hi; }
    else if (s < 64) { lhi = (hi << s) | (lo >> (64 - s)); llo = lo << s; }
    else             { lhi = lo << (s - 64); llo = 0ULL; }
    if (lhi)      down = __builtin_clzll(lhi);
    else if (llo) down = 64 + __builtin_clzll(llo);
    return min(up, down);
}

__device__ inline u64 asm64(unsigned int (*p)[WW], int k0, int j) {
    return (u64)p[k0][j] | ((u64)p[k0 + 1][j] << 16)
         | ((u64)p[k0 + 2][j] << 32) | ((u64)p[k0 + 3][j] << 48);
}

// Single fused kernel. block = (pair n, row tile t), 1024 threads.
//   stage A: distributed argmax (40 uchar4 units per block, coalesced)
//   grid barrier: arrival = 1 release-RMW per block; wait = relaxed LOAD
//     spin + s_sleep (R9's RMW spin serialized ~40us; loads don't).
//   stage B: column bitmasks -> bit-parallel edge -> column EDT (bit-trick)
//            -> row EDT (early-exit expanding ring) -> loss -> ticket finale
__global__ __launch_bounds__(1024) void k_all(
        const float* __restrict__ Ls, const float* __restrict__ Lt,
        unsigned char* __restrict__ ps, unsigned char* __restrict__ pt,
        float* __restrict__ sums, int* __restrict__ done, int* __restrict__ bar,
        float* __restrict__ out) {
    int tid = threadIdx.x;

    // ---- stage A: argmax over channels, 4 pixels/unit ----
    if (tid < UPB) {
        int u = blockIdx.x * UPB + tid;
        if (u < NUNIT) {
            const float* L; unsigned char* dst;
            int p4 = u & (NUNIT / 2 - 1);
            if (u < NUNIT / 2) { L = Ls; dst = ps; }
            else               { L = Lt; dst = pt; }
            int b = p4 >> 12;                 // / (HW/4)
            int q4 = p4 & (HW / 4 - 1);
            const float4* base = (const float4*)(L + (size_t)b * CC * HW) + q4;
            float4 best = base[0];
            uchar4 bi = make_uchar4(0, 0, 0, 0);
#pragma unroll
            for (int c = 1; c < CC; ++c) {
                float4 v = base[(size_t)c * (HW / 4)];
                if (v.x > best.x) { best.x = v.x; bi.x = (unsigned char)c; }
                if (v.y > best.y) { best.y = v.y; bi.y = (unsigned char)c; }
                if (v.z > best.z) { best.z = v.z; bi.z = (unsigned char)c; }
                if (v.w > best.w) { best.w = v.w; bi.w = (unsigned char)c; }
            }
            ((uchar4*)dst)[b * (HW / 4) + q4] = bi;
        }
    }

    // ---- grid barrier (device-scope; all 416 blocks co-resident) ----
    __syncthreads();
    if (tid == 0) {
        __threadfence();                      // publish stage-A stores
        __hip_atomic_fetch_add(bar, 1, __ATOMIC_RELEASE, __HIP_MEMORY_SCOPE_AGENT);
        while (__hip_atomic_load(bar, __ATOMIC_RELAXED, __HIP_MEMORY_SCOPE_AGENT) < NBLK)
            __builtin_amdgcn_s_sleep(2);      // load-spin, no RMW contention
        __threadfence();                      // acquire
    }
    __syncthreads();

    // ---- stage B ----
    int n = blockIdx.x >> 4;          // pair
    int t = blockIdx.x & 15;          // row tile
    int k = tid >> 7;                 // 0..7 (chunk in ph1, row r in ph3)
    int j = tid & (WW - 1);
    int b = n / (CC - 1), c = 1 + (n - b * (CC - 1));
    const unsigned char* P = ps + b * HW;
    const unsigned char* T = pt + b * HW;
    const float* Lp = Ls + (size_t)(b * CC + c) * HW;

    int i = t * RPB + k;              // this thread's output row (phase 3)
    float lv = Lp[i * WW + j];        // hoisted, coalesced

    // phase 1: 16-row chunk bitmasks (coalesced across j)
    unsigned int s16 = 0, t16 = 0, h16 = 0;
    int i0 = k << 4;
#pragma unroll
    for (int r = 0; r < 16; ++r) {
        int off = (i0 + r) * WW + j;
        if (P[off] == c)              s16 |= 1u << r;
        if (T[off] == c)              t16 |= 1u << r;
        if (Lp[off] > 0.5f)           h16 |= 1u << r;
    }
    __shared__ unsigned int pS[8][WW], pT[8][WW], pH[8][WW];
    pS[k][j] = s16; pT[k][j] = t16; pH[k][j] = h16;
    __syncthreads();

    // phase 2: erosion/edge bit-math, 128 threads
    __shared__ ulonglong2 colFP[WW], colET[WW], colES[WW];
    __shared__ int sfl[2];
    if (tid < WW) {
        u64 ms0 = asm64(pS, 0, j), ms1 = asm64(pS, 4, j);
        u64 mt0 = asm64(pT, 0, j), mt1 = asm64(pT, 4, j);
        u64 hi0 = asm64(pH, 0, j), hi1 = asm64(pH, 4, j);
        u64 Lsx = 0, Lsy = 0, Ltx = 0, Lty = 0, Rsx = 0, Rsy = 0, Rtx = 0, Rty = 0;
        if (j > 0)      { Lsx = asm64(pS, 0, j - 1); Lsy = asm64(pS, 4, j - 1);
                          Ltx = asm64(pT, 0, j - 1); Lty = asm64(pT, 4, j - 1); }
        if (j < WW - 1) { Rsx = asm64(pS, 0, j + 1); Rsy = asm64(pS, 4, j + 1);
                          Rtx = asm64(pT, 0, j + 1); Rty = asm64(pT, 4, j + 1); }

        // erosion: m & up & down & left & right; shifts insert 0 (border erodes)
        u64 U0 = ms0 << 1, U1 = (ms1 << 1) | (ms0 >> 63);
        u64 D0 = (ms0 >> 1) | (ms1 << 63), D1 = ms1 >> 1;
        u64 er0 = ms0 & U0 & D0 & Lsx & Rsx;
        u64 er1 = ms1 & U1 & D1 & Lsy & Rsy;
        u64 es0 = ms0 & ~er0, es1 = ms1 & ~er1;

        u64 Ut0 = mt0 << 1, Ut1 = (mt1 << 1) | (mt0 >> 63);
        u64 Dt0 = (mt0 >> 1) | (mt1 << 63), Dt1 = mt1 >> 1;
        u64 ert0 = mt0 & Ut0 & Dt0 & Ltx & Rtx;
        u64 ert1 = mt1 & Ut1 & Dt1 & Lty & Rty;
        u64 et0 = mt0 & ~ert0, et1 = mt1 & ~ert1;

        u64 fp0 = es0 & hi0, fp1 = es1 & hi1;   // pred = es*logit > 0.5

        colFP[j] = make_ulonglong2(fp0, fp1);
        colET[j] = make_ulonglong2(et0, et1);
        colES[j] = make_ulonglong2(es0, es1);

        u64 bFgP = __ballot((fp0 | fp1) != 0ull);
        u64 bBgP = __ballot((fp0 & fp1) != ~0ull);
        u64 bFgT = __ballot((et0 | et1) != 0ull);
        u64 bBgT = __ballot((et0 & et1) != ~0ull);
        if ((tid & 63) == 0) {
            sfl[tid >> 6] = (bFgP ? 1 : 0) | (bBgP ? 2 : 0)
                          | (bFgT ? 4 : 0) | (bBgT ? 8 : 0);
        }
    }
    __syncthreads();

    // phase 3: column EDT + expanding-ring row EDT + loss
    ulonglong2 mP = colFP[j];
    ulonglong2 mT = colET[j];
    ulonglong2 eS = colES[j];
    int f = sfl[0] | sfl[1];
    bool aP = (f & 3) == 3, aT = (f & 12) == 12;

    int dP  = nbd(mP.x, mP.y, i);
    int dPb = nbd(~mP.x, ~mP.y, i);
    int dT  = nbd(mT.x, mT.y, i);
    int dTb = nbd(~mT.x, ~mT.y, i);

    __shared__ uchar4 sq[RPB][WW];    // d1 per map (255 sentinel; squared on read)
    sq[k][j] = make_uchar4((unsigned char)dP, (unsigned char)dPb,
                           (unsigned char)dT, (unsigned char)dTb);
    __syncthreads();

    int bP = dP * dP, bPb = dPb * dPb, bT = dT * dT, bTb = dTb * dTb;
    int need = 0;
    if (aP) need = max(bP, bPb);
    if (aT) need = max(need, max(bT, bTb));
    // expanding ring: candidates at radius rad are >= rad^2, so once
    // rad^2 >= need (best over maps actually used), the min is final.
    for (int rad = 1; rad < WW; ++rad) {
        int rr = rad * rad;
        if (rr >= need) break;
        if (j >= rad) {
            uchar4 s = sq[k][j - rad];
            bP  = min(bP,  (int)s.x * s.x + rr); bPb = min(bPb, (int)s.y * s.y + rr);
            bT  = min(bT,  (int)s.z * s.z + rr); bTb = min(bTb, (int)s.w * s.w + rr);
        }
        if (j + rad < WW) {
            uchar4 s = sq[k][j + rad];
            bP  = min(bP,  (int)s.x * s.x + rr); bPb = min(bPb, (int)s.y * s.y + rr);
            bT  = min(bT,  (int)s.z * s.z + rr); bTb = min(bTb, (int)s.w * s.w + rr);
        }
        need = 0;
        if (aP) need = max(bP, bPb);
        if (aT) need = max(need, max(bT, bTb));
    }

    float fieldP = aP ? (float)(bP + bPb) : 0.0f;
    float fieldT = aT ? (float)(bT + bTb) : 0.0f;

    bool es = ((i < 64 ? (eS.x >> i) : (eS.y >> (i - 64))) & 1ull) != 0;
    bool et = ((i < 64 ? (mT.x >> i) : (mT.y >> (i - 64))) & 1ull) != 0;
    float predv = es ? lv : 0.0f;
    float targv = et ? (float)c : 0.0f;
    float diff = predv - targv;
    float v = diff * diff * (fieldP + fieldT);

    for (int o = 32; o > 0; o >>= 1) v += __shfl_down(v, o);
    __shared__ float wsum[16];
    __shared__ int won;
    int lane = tid & 63, w = tid >> 6;
    if (lane == 0) wsum[w] = v;
    if (tid == 0) won = 0;
    __syncthreads();
    if (tid == 0) {
        float tot = 0.0f;
#pragma unroll
        for (int q = 0; q < 16; ++q) tot += wsum[q];
        atomicAdd(&sums[n], tot);
        __threadfence();                       // sums visible before ticket
        if (atomicAdd(done, 1) == NBLK - 1) won = 1;
    }
    __syncthreads();
    if (won && tid < 64) {                     // wave 0 of the last block
        float vv = 0.0f;
        if (tid < NPAIR) {
            float hd = atomicAdd(&sums[tid], 0.0f) * (1.0f / (float)HW);
            vv = logf(hd + 1.0f);
        }
        for (int o = 32; o > 0; o >>= 1) vv += __shfl_down(vv, o);
        if (tid == 0) out[0] = 0.5f * vv;      // (1 - LOSS_WEIGHT) * sum
    }
}

extern "C" void kernel_launch(void* const* d_in, const int* in_sizes, int n_in,
                              void* d_out, int out_size, void* d_ws, size_t ws_size,
                              hipStream_t stream) {
    const float* Ls = (const float*)d_in[0];
    const float* Lt = (const float*)d_in[1];
    float* out = (float*)d_out;

    char* w = (char*)d_ws;
    unsigned char* ps   = (unsigned char*)(w);
    unsigned char* pt   = (unsigned char*)(w + 32768);
    float*         sums = (float*)        (w + 65536);
    int*           done = (int*)          (w + 65664);
    int*           bar  = (int*)          (w + 65668);

    // zero sums[26] + done + bar (graph-capturable async memset)
    hipMemsetAsync(w + 65536, 0, 136, stream);
    k_all<<<NBLK, 1024, 0, stream>>>(Ls, Lt, ps, pt, sums, done, bar, out);
}

// Round 12
// 71.747 us; speedup vs baseline: 1.4852x; 1.4852x over previous
//
#include <hip/hip_runtime.h>
#include <math.h>
#include <limits.h>

#define HH 128
#define WW 128
#define HW (HH*WW)
#define BB 2
#define CC 14
#define NPAIR 26   // B * (C-1)
#define RPB 8                      // rows per k_C block
#define NBLK (NPAIR * (HH / RPB))  // 416 k_C blocks

typedef unsigned long long u64;

// ---------------------------------------------------------------------------
// ws layout (bytes):
//   lab   : [BB][HW] u8   @ 0      (32768)  packed argmax labels: ps | pt<<4
//   hb    : [BB][HW] u16  @ 32768  (65536)  bit c-1 = (Ls[c] > 0.5), c=1..13
//   sums  : [NPAIR] f32   @ 98304  (104)
//   done  : int           @ 98432  (4)      last-block ticket
// ---------------------------------------------------------------------------

// distance from row i to nearest set bit in 128-bit mask {lo,hi}; 255 if empty.
// i is wave-uniform in k_C -> uniform branches.
__device__ inline int nbd(u64 lo, u64 hi, int i) {
    int up = 255, down = 255;
    u64 slo, shi;
    if (i == 0)      { slo = lo; shi = hi; }
    else if (i < 64) { slo = (lo >> i) | (hi << (64 - i)); shi = hi >> i; }
    else             { slo = hi >> (i - 64); shi = 0ULL; }
    if (slo)      up = __builtin_ctzll(slo);
    else if (shi) up = 64 + __builtin_ctzll(shi);
    int s = 127 - i;
    u64 llo, lhi;
    if (s == 0)      { llo = lo; lhi = hi; }
    else if (s < 64) { lhi = (hi << s) | (lo >> (64 - s)); llo = lo << s; }
    else             { lhi = lo << (s - 64); llo = 0ULL; }
    if (lhi)      down = __builtin_clzll(lhi);
    else if (llo) down = 64 + __builtin_clzll(llo);
    return min(up, down);
}

// fused argmax (student+teacher) + packed labels + student logit>0.5 bitmask.
// 4 pixels/thread (float4); 8192 threads. block 0 zeroes sums/done.
__global__ void k_argmax(const float* __restrict__ Ls, const float* __restrict__ Lt,
                         unsigned char* __restrict__ lab, unsigned short* __restrict__ hb,
                         float* __restrict__ sums, int* __restrict__ done) {
    if (blockIdx.x == 0) {
        if (threadIdx.x < NPAIR) sums[threadIdx.x] = 0.0f;
        if (threadIdx.x == 0) *done = 0;
    }
    int p4 = blockIdx.x * blockDim.x + threadIdx.x;   // 0..8191
    if (p4 >= BB * HW / 4) return;
    int b = p4 >> 12;                 // / (HW/4)
    int q4 = p4 & (HW / 4 - 1);
    const float4* bs = (const float4*)(Ls + (size_t)b * CC * HW) + q4;
    const float4* bt = (const float4*)(Lt + (size_t)b * CC * HW) + q4;
    float4 mS = bs[0], mT = bt[0];
    uchar4 iS = make_uchar4(0, 0, 0, 0), iT = make_uchar4(0, 0, 0, 0);
    ushort4 hm = make_ushort4(0, 0, 0, 0);
#pragma unroll
    for (int c = 1; c < CC; ++c) {
        float4 v = bs[(size_t)c * (HW / 4)];
        if (v.x > mS.x) { mS.x = v.x; iS.x = (unsigned char)c; }   // first-max tie rule
        if (v.y > mS.y) { mS.y = v.y; iS.y = (unsigned char)c; }
        if (v.z > mS.z) { mS.z = v.z; iS.z = (unsigned char)c; }
        if (v.w > mS.w) { mS.w = v.w; iS.w = (unsigned char)c; }
        unsigned short bit = (unsigned short)(1u << (c - 1));
        if (v.x > 0.5f) hm.x |= bit;
        if (v.y > 0.5f) hm.y |= bit;
        if (v.z > 0.5f) hm.z |= bit;
        if (v.w > 0.5f) hm.w |= bit;
        float4 u = bt[(size_t)c * (HW / 4)];
        if (u.x > mT.x) { mT.x = u.x; iT.x = (unsigned char)c; }
        if (u.y > mT.y) { mT.y = u.y; iT.y = (unsigned char)c; }
        if (u.z > mT.z) { mT.z = u.z; iT.z = (unsigned char)c; }
        if (u.w > mT.w) { mT.w = u.w; iT.w = (unsigned char)c; }
    }
    uchar4 pk = make_uchar4((unsigned char)(iS.x | (iT.x << 4)),
                            (unsigned char)(iS.y | (iT.y << 4)),
                            (unsigned char)(iS.z | (iT.z << 4)),
                            (unsigned char)(iS.w | (iT.w << 4)));
    ((uchar4*)lab)[b * (HW / 4) + q4] = pk;
    ((ushort4*)hb)[b * (HW / 4) + q4] = hm;
}

__device__ inline u64 asm64(unsigned int (*p)[WW], int k0, int j) {
    return (u64)p[k0][j] | ((u64)p[k0 + 1][j] << 16)
         | ((u64)p[k0 + 2][j] << 32) | ((u64)p[k0 + 3][j] << 48);
}

// One fused kernel per (pair, 8-row tile):
//   phase 1: column bitmask build from packed labels + hbits (2 loads/row)
//   phase 2: bit-parallel erosion/edge -> per-column masks in LDS (+ flags)
//   phase 3: column EDT (bit-trick) -> row EDT (early-exit expanding ring)
//            -> loss accumulation -> last-block final reduction.
// block = (pair n, row tile t), 1024 threads = (chunk k / row r, column j).
__global__ __launch_bounds__(1024) void k_C(
        const unsigned char* __restrict__ lab, const unsigned short* __restrict__ hb,
        const float* __restrict__ Ls,
        float* __restrict__ sums, int* __restrict__ done, float* __restrict__ out) {
    int n = blockIdx.x >> 4;          // pair
    int t = blockIdx.x & 15;          // row tile
    int tid = threadIdx.x;
    int k = tid >> 7;                 // 0..7 (chunk in ph1, row r in ph3)
    int j = tid & (WW - 1);
    int b = n / (CC - 1), c = 1 + (n - b * (CC - 1));
    const unsigned char*  LB = lab + b * HW;
    const unsigned short* HB = hb + b * HW;
    const float* Lp = Ls + (size_t)(b * CC + c) * HW;

    int i = t * RPB + k;              // this thread's output row (phase 3)
    float lv = Lp[i * WW + j];        // hoisted, coalesced

    // phase 1: 16-row chunk bitmasks (coalesced across j; 2 int loads/row)
    unsigned int s16 = 0, t16 = 0, h16 = 0;
    int i0 = k << 4;
    unsigned int hbit = 1u << (c - 1);
#pragma unroll
    for (int r = 0; r < 16; ++r) {
        int off = (i0 + r) * WW + j;
        unsigned int lbv = LB[off];
        if ((lbv & 15u) == (unsigned)c)  s16 |= 1u << r;
        if ((lbv >> 4)  == (unsigned)c)  t16 |= 1u << r;
        if (HB[off] & hbit)              h16 |= 1u << r;
    }
    __shared__ unsigned int pS[8][WW], pT[8][WW], pH[8][WW];
    pS[k][j] = s16; pT[k][j] = t16; pH[k][j] = h16;
    __syncthreads();

    // phase 2: erosion/edge bit-math, 128 threads
    __shared__ ulonglong2 colFP[WW], colET[WW], colES[WW];
    __shared__ int sfl[2];
    if (tid < WW) {
        u64 ms0 = asm64(pS, 0, j), ms1 = asm64(pS, 4, j);
        u64 mt0 = asm64(pT, 0, j), mt1 = asm64(pT, 4, j);
        u64 hi0 = asm64(pH, 0, j), hi1 = asm64(pH, 4, j);
        u64 Lsx = 0, Lsy = 0, Ltx = 0, Lty = 0, Rsx = 0, Rsy = 0, Rtx = 0, Rty = 0;
        if (j > 0)      { Lsx = asm64(pS, 0, j - 1); Lsy = asm64(pS, 4, j - 1);
                          Ltx = asm64(pT, 0, j - 1); Lty = asm64(pT, 4, j - 1); }
        if (j < WW - 1) { Rsx = asm64(pS, 0, j + 1); Rsy = asm64(pS, 4, j + 1);
                          Rtx = asm64(pT, 0, j + 1); Rty = asm64(pT, 4, j + 1); }

        // erosion: m & up & down & left & right; shifts insert 0 (border erodes)
        u64 U0 = ms0 << 1, U1 = (ms1 << 1) | (ms0 >> 63);
        u64 D0 = (ms0 >> 1) | (ms1 << 63), D1 = ms1 >> 1;
        u64 er0 = ms0 & U0 & D0 & Lsx & Rsx;
        u64 er1 = ms1 & U1 & D1 & Lsy & Rsy;
        u64 es0 = ms0 & ~er0, es1 = ms1 & ~er1;

        u64 Ut0 = mt0 << 1, Ut1 = (mt1 << 1) | (mt0 >> 63);
        u64 Dt0 = (mt0 >> 1) | (mt1 << 63), Dt1 = mt1 >> 1;
        u64 ert0 = mt0 & Ut0 & Dt0 & Ltx & Rtx;
        u64 ert1 = mt1 & Ut1 & Dt1 & Lty & Rty;
        u64 et0 = mt0 & ~ert0, et1 = mt1 & ~ert1;

        u64 fp0 = es0 & hi0, fp1 = es1 & hi1;   // pred = es*logit > 0.5

        colFP[j] = make_ulonglong2(fp0, fp1);
        colET[j] = make_ulonglong2(et0, et1);
        colES[j] = make_ulonglong2(es0, es1);

        u64 bFgP = __ballot((fp0 | fp1) != 0ull);
        u64 bBgP = __ballot((fp0 & fp1) != ~0ull);
        u64 bFgT = __ballot((et0 | et1) != 0ull);
        u64 bBgT = __ballot((et0 & et1) != ~0ull);
        if ((tid & 63) == 0) {
            sfl[tid >> 6] = (bFgP ? 1 : 0) | (bBgP ? 2 : 0)
                          | (bFgT ? 4 : 0) | (bBgT ? 8 : 0);
        }
    }
    __syncthreads();

    // phase 3: column EDT + expanding-ring row EDT + loss
    ulonglong2 mP = colFP[j];
    ulonglong2 mT = colET[j];
    ulonglong2 eS = colES[j];
    int f = sfl[0] | sfl[1];
    bool aP = (f & 3) == 3, aT = (f & 12) == 12;

    int dP  = nbd(mP.x, mP.y, i);
    int dPb = nbd(~mP.x, ~mP.y, i);
    int dT  = nbd(mT.x, mT.y, i);
    int dTb = nbd(~mT.x, ~mT.y, i);

    __shared__ uchar4 sq[RPB][WW];    // d1 per map (255 sentinel; squared on read)
    sq[k][j] = make_uchar4((unsigned char)dP, (unsigned char)dPb,
                           (unsigned char)dT, (unsigned char)dTb);
    __syncthreads();

    int bP = dP * dP, bPb = dPb * dPb, bT = dT * dT, bTb = dTb * dTb;
    int need = 0;
    if (aP) need = max(bP, bPb);
    if (aT) need = max(need, max(bT, bTb));
    // expanding ring: candidates at radius rad are >= rad^2, so once
    // rad^2 >= need (best over maps actually used), the min is final.
    for (int rad = 1; rad < WW; ++rad) {
        int rr = rad * rad;
        if (rr >= need) break;
        if (j >= rad) {
            uchar4 s = sq[k][j - rad];
            bP  = min(bP,  (int)s.x * s.x + rr); bPb = min(bPb, (int)s.y * s.y + rr);
            bT  = min(bT,  (int)s.z * s.z + rr); bTb = min(bTb, (int)s.w * s.w + rr);
        }
        if (j + rad < WW) {
            uchar4 s = sq[k][j + rad];
            bP  = min(bP,  (int)s.x * s.x + rr); bPb = min(bPb, (int)s.y * s.y + rr);
            bT  = min(bT,  (int)s.z * s.z + rr); bTb = min(bTb, (int)s.w * s.w + rr);
        }
        need = 0;
        if (aP) need = max(bP, bPb);
        if (aT) need = max(need, max(bT, bTb));
    }

    float fieldP = aP ? (float)(bP + bPb) : 0.0f;
    float fieldT = aT ? (float)(bT + bTb) : 0.0f;

    bool es = ((i < 64 ? (eS.x >> i) : (eS.y >> (i - 64))) & 1ull) != 0;
    bool et = ((i < 64 ? (mT.x >> i) : (mT.y >> (i - 64))) & 1ull) != 0;
    float predv = es ? lv : 0.0f;
    float targv = et ? (float)c : 0.0f;
    float diff = predv - targv;
    float v = diff * diff * (fieldP + fieldT);

    for (int o = 32; o > 0; o >>= 1) v += __shfl_down(v, o);
    __shared__ float wsum[16];
    __shared__ int won;
    int lane = tid & 63, w = tid >> 6;
    if (lane == 0) wsum[w] = v;
    if (tid == 0) won = 0;
    __syncthreads();
    if (tid == 0) {
        float tot = 0.0f;
#pragma unroll
        for (int q = 0; q < 16; ++q) tot += wsum[q];
        atomicAdd(&sums[n], tot);
        __threadfence();                       // sums visible before ticket
        if (atomicAdd(done, 1) == NBLK - 1) won = 1;
    }
    __syncthreads();
    if (won && tid < 64) {                     // wave 0 of the last block
        float vv = 0.0f;
        if (tid < NPAIR) {
            float hd = atomicAdd(&sums[tid], 0.0f) * (1.0f / (float)HW);
            vv = logf(hd + 1.0f);
        }
        for (int o = 32; o > 0; o >>= 1) vv += __shfl_down(vv, o);
        if (tid == 0) out[0] = 0.5f * vv;      // (1 - LOSS_WEIGHT) * sum
    }
}

extern "C" void kernel_launch(void* const* d_in, const int* in_sizes, int n_in,
                              void* d_out, int out_size, void* d_ws, size_t ws_size,
                              hipStream_t stream) {
    const float* Ls = (const float*)d_in[0];
    const float* Lt = (const float*)d_in[1];
    float* out = (float*)d_out;

    char* w = (char*)d_ws;
    unsigned char*  lab  = (unsigned char*) (w);
    unsigned short* hbm  = (unsigned short*)(w + 32768);
    float*          sums = (float*)         (w + 98304);
    int*            done = (int*)           (w + 98432);

    k_argmax<<<BB * HW / 4 / 256, 256, 0, stream>>>(Ls, Lt, lab, hbm, sums, done);
    k_C<<<NBLK, 1024, 0, stream>>>(lab, hbm, Ls, sums, done, out);
}